// Round 11
// baseline (515.432 us; speedup 1.0000x reference)
//
#include <hip/hip_runtime.h>
#include <math.h>

// ---------------------------------------------------------------------------
// Round 22 — attn occupancy fix: unroll pass loop into grid, heavy-first.
//   K2: grid (16,16,4) = 1024 blocks, one q-tile per block, qt = 15-bx
//   (heavy blocks dispatch FIRST -> LPT schedule, tail = 2-tile blocks).
//   4 blocks/CU (was 2) -> 4 waves/SIMD latency hiding. Body unchanged
//   (round-19 structure: 4 waves x 32 rows, fragment amortization,
//   XOR-swizzle, defer-max, partial-l, setprio).
//   K1: reverted to round-20 p2 core (256² 8-phase was neutral at this
//   shape: 1 block/CU @128KB LDS, K too short to fill the pipeline).
//   K0/K3 unchanged.
// ---------------------------------------------------------------------------

typedef __attribute__((ext_vector_type(8))) __bf16 bf16x8;
typedef __attribute__((ext_vector_type(8))) short  short8;
typedef __attribute__((ext_vector_type(4))) short  s16x4;
typedef __attribute__((ext_vector_type(4))) float  f32x4;

#define MFMA16(a, b, c) __builtin_amdgcn_mfma_f32_16x16x32_bf16((a), (b), (c), 0, 0, 0)

static constexpr int    BATCH = 4;
static constexpr int    SEQ   = 2048;
static constexpr int    DIM   = 1024;
static constexpr int    NH    = 16;
static constexpr int    HD    = 64;
static constexpr size_t BHSD  = (size_t)BATCH * NH * SEQ * HD;  // 8388608
static constexpr float  NEGINF = -1e9f;
static constexpr int    PS_LD  = 72;

__device__ __forceinline__ short f2bf(float f) {
    union { float f; unsigned u; } v; v.f = f;
    unsigned r = v.u + 0x7fffu + ((v.u >> 16) & 1u);  // RNE
    return (short)(r >> 16);
}

__device__ __forceinline__ short8 cvt8(const f32x4 lo, const f32x4 hi) {
    short8 r;
    r[0] = f2bf(lo[0]); r[1] = f2bf(lo[1]); r[2] = f2bf(lo[2]); r[3] = f2bf(lo[3]);
    r[4] = f2bf(hi[0]); r[5] = f2bf(hi[1]); r[6] = f2bf(hi[2]); r[7] = f2bf(hi[3]);
    return r;
}

template <bool F32>
__device__ __forceinline__ short8 ld8(const void* p, size_t row, int K, int k) {
    if constexpr (F32) {
        const float* f = (const float*)p;
        f32x4 lo = *(const f32x4*)&f[row * (size_t)K + k];
        f32x4 hi = *(const f32x4*)&f[row * (size_t)K + k + 4];
        return cvt8(lo, hi);
    } else {
        const short* s = (const short*)p;
        return *(const short8*)&s[row * (size_t)K + k];
    }
}

__device__ __forceinline__ void gload16(const void* g, void* lds) {
    __builtin_amdgcn_global_load_lds(
        (const __attribute__((address_space(1))) void*)g,
        (__attribute__((address_space(3))) void*)lds, 16, 0, 0);
}

// ---------------------------------------------------------------------------
// K0: one-shot bf16 conversion of X/Wqkv/Wout + RoPE trig tables.
// ---------------------------------------------------------------------------
__global__ __launch_bounds__(256) void prep_kernel(
    const float* __restrict__ X, const float* __restrict__ Wq,
    const float* __restrict__ Wo, short* __restrict__ Xb,
    short* __restrict__ Wqb, short* __restrict__ Wob,
    float* __restrict__ cosT, float* __restrict__ sinT) {
    const int stride = gridDim.x * blockDim.x;
    for (int idx = blockIdx.x * blockDim.x + threadIdx.x; idx < 3211264; idx += stride) {
        if (idx < 3145728) {
            const float* src; short* dst; int off;
            if (idx < 2097152)      { src = X;  dst = Xb;  off = idx; }
            else if (idx < 2883584) { src = Wq; dst = Wqb; off = idx - 2097152; }
            else                    { src = Wo; dst = Wob; off = idx - 2883584; }
            f32x4 v = *(const f32x4*)&src[(size_t)off * 4];
            s16x4 r;
            r[0] = f2bf(v[0]); r[1] = f2bf(v[1]); r[2] = f2bf(v[2]); r[3] = f2bf(v[3]);
            *(s16x4*)&dst[(size_t)off * 4] = r;
        } else {
            int r = idx - 3145728;
            int s = r >> 5, d = r & 31;
            float ang = (float)s * __expf(-0.28782313662425574f * (float)d);
            float sn, cs;
            sincosf(ang, &sn, &cs);
            cosT[r] = cs; sinT[r] = sn;
        }
    }
}

// ---------------------------------------------------------------------------
// GEMM core (fallback, reg-staged fp32): C(128x128) += A(128xK)*B(128xK)^T.
// ---------------------------------------------------------------------------
template <bool AF32, bool BF32>
__device__ __forceinline__ void gemm128_core(
    const void* __restrict__ A, const void* __restrict__ B, int K,
    short* As, short* Bs, int bm, int bn, f32x4 acc[4][4]) {
    const int tid  = threadIdx.x;
    const int lane = tid & 63;
    const int wave = tid >> 6;
    const int quad = lane >> 4;
    const int col  = lane & 15;
    const int wm   = (wave & 1) * 64;
    const int wn   = (wave >> 1) * 64;

    const int r0 = tid >> 2;
    const int r1 = (tid + 256) >> 2;
    const int ko = (tid & 3) * 8;

#pragma unroll
    for (int i = 0; i < 4; ++i)
#pragma unroll
        for (int j = 0; j < 4; ++j) acc[i][j] = f32x4{0.f, 0.f, 0.f, 0.f};

#pragma unroll 1
    for (int k0 = 0; k0 < K; k0 += 32) {
        short8 a0 = ld8<AF32>(A, (size_t)(bm + r0), K, k0 + ko);
        short8 a1 = ld8<AF32>(A, (size_t)(bm + r1), K, k0 + ko);
        short8 b0 = ld8<BF32>(B, (size_t)(bn + r0), K, k0 + ko);
        short8 b1 = ld8<BF32>(B, (size_t)(bn + r1), K, k0 + ko);
        __syncthreads();
        *(short8*)&As[tid * 8]         = a0;
        *(short8*)&As[(tid + 256) * 8] = a1;
        *(short8*)&Bs[tid * 8]         = b0;
        *(short8*)&Bs[(tid + 256) * 8] = b1;
        __syncthreads();

        bf16x8 af[4], bfr[4];
#pragma unroll
        for (int i = 0; i < 4; ++i)
            af[i] = *(const bf16x8*)&As[(wm + i * 16 + col) * 32 + quad * 8];
#pragma unroll
        for (int j = 0; j < 4; ++j)
            bfr[j] = *(const bf16x8*)&Bs[(wn + j * 16 + col) * 32 + quad * 8];
#pragma unroll
        for (int i = 0; i < 4; ++i)
#pragma unroll
            for (int j = 0; j < 4; ++j)
                acc[i][j] = MFMA16(af[i], bfr[j], acc[i][j]);
    }
}

// ---------------------------------------------------------------------------
// GEMM core p2 (bf16): BK=64 dbuf gload_lds, counted vmcnt, raw barriers,
// source-pre-swizzled LDS.
// ---------------------------------------------------------------------------
__device__ __forceinline__ void gemm128_p2(
    const short* __restrict__ A, const short* __restrict__ B, int K,
    short* As, short* Bs, int bm, int bn, f32x4 acc[4][4]) {
    const int tid  = threadIdx.x;
    const int lane = tid & 63;
    const int wave = tid >> 6;
    const int quad = lane >> 4;
    const int col  = lane & 15;
    const int wm   = (wave & 1) * 64;
    const int wn   = (wave >> 1) * 64;

    const int nt = K >> 6;
    const int rr = tid >> 3;
    const int swk = (((tid & 7) ^ (rr & 7)) << 3);
    const short* Ab = &A[(size_t)(bm + rr) * K + swk];
    const short* Bb = &B[(size_t)(bn + rr) * K + swk];

#pragma unroll
    for (int i = 0; i < 4; ++i)
#pragma unroll
        for (int j = 0; j < 4; ++j) acc[i][j] = f32x4{0.f, 0.f, 0.f, 0.f};

#define STAGE_TILE(c)                                                         \
    {                                                                         \
        const int s_ = (c) & 1;                                               \
        const int k0_ = (c) << 6;                                             \
        _Pragma("unroll")                                                     \
        for (int q = 0; q < 4; ++q) {                                         \
            gload16(Ab + (size_t)(q * 32) * K + k0_,                          \
                    &As[s_ * 8192 + q * 2048 + wave * 512]);                  \
            gload16(Bb + (size_t)(q * 32) * K + k0_,                          \
                    &Bs[s_ * 8192 + q * 2048 + wave * 512]);                  \
        }                                                                     \
    }

    STAGE_TILE(0);
    STAGE_TILE(1);

    const int pc0 = ((quad) ^ (col & 7)) << 3;
    const int pc1 = ((4 | quad) ^ (col & 7)) << 3;

#pragma unroll 1
    for (int c = 0; c < nt; ++c) {
        const int s = c & 1;
        if (c + 1 < nt) { asm volatile("s_waitcnt vmcnt(8)" ::: "memory"); }
        else            { asm volatile("s_waitcnt vmcnt(0)" ::: "memory"); }
        __builtin_amdgcn_s_barrier();

        const short* Asl = &As[s * 8192];
        const short* Bsl = &Bs[s * 8192];
        bf16x8 af[4][2], bfr[4][2];
#pragma unroll
        for (int i = 0; i < 4; ++i) {
            const int r = (wm + i * 16 + col) * 64;
            af[i][0] = *(const bf16x8*)&Asl[r + pc0];
            af[i][1] = *(const bf16x8*)&Asl[r + pc1];
        }
#pragma unroll
        for (int j = 0; j < 4; ++j) {
            const int r = (wn + j * 16 + col) * 64;
            bfr[j][0] = *(const bf16x8*)&Bsl[r + pc0];
            bfr[j][1] = *(const bf16x8*)&Bsl[r + pc1];
        }
#pragma unroll
        for (int kk = 0; kk < 2; ++kk)
#pragma unroll
            for (int i = 0; i < 4; ++i)
#pragma unroll
                for (int j = 0; j < 4; ++j)
                    acc[i][j] = MFMA16(af[i][kk], bfr[j][kk], acc[i][j]);

        __builtin_amdgcn_s_barrier();
        if (c + 2 < nt) STAGE_TILE(c + 2);
    }
#undef STAGE_TILE
}

// ---------------------------------------------------------------------------
// K1: QKV GEMM + RoPE. grid=(24, 64). Q,K row-major [B,H,S,D]; V transposed
// [B,H,D,S]. PRE: bf16 inputs (p2 core) + table RoPE.
// ---------------------------------------------------------------------------
template <bool PRE>
__global__ __launch_bounds__(256, 2) void qkv_rope_kernel(
    const void* __restrict__ X, const void* __restrict__ W,
    const float* __restrict__ cosT, const float* __restrict__ sinT,
    short* __restrict__ Qo, short* __restrict__ Ko, short* __restrict__ VT) {
    __shared__ __align__(16) short As[2 * 8192];
    __shared__ __align__(16) short Bs[2 * 8192];
    const int bm = blockIdx.y * 128, bn = blockIdx.x * 128;
    const int lane = threadIdx.x & 63, wave = threadIdx.x >> 6;
    const int quad = lane >> 4, col = lane & 15;
    const int wm = (wave & 1) * 64, wn = (wave >> 1) * 64;

    f32x4 acc[4][4];
    if constexpr (PRE)
        gemm128_p2((const short*)X, (const short*)W, 1024, As, Bs, bm, bn, acc);
    else
        gemm128_core<true, true>(X, W, 1024, As, Bs, bm, bn, acc);

    const int n0    = bn + wn;
    const int which = n0 >> 10;
    const int h     = (n0 >> 6) & 15;

    if (which == 2) {
#pragma unroll
        for (int i = 0; i < 4; ++i) {
            int    m = bm + wm + i * 16 + quad * 4;
            int    b = m >> 11, s = m & 2047;
            size_t rowb = (size_t)(b * NH + h) * HD;
#pragma unroll
            for (int j = 0; j < 4; ++j) {
                int   d = j * 16 + col;
                s16x4 pk;
                pk[0] = f2bf(acc[i][j][0]); pk[1] = f2bf(acc[i][j][1]);
                pk[2] = f2bf(acc[i][j][2]); pk[3] = f2bf(acc[i][j][3]);
                *(s16x4*)&VT[(rowb + d) * SEQ + s] = pk;
            }
        }
    } else {
        short* dst = which ? Ko : Qo;
#pragma unroll
        for (int i = 0; i < 4; ++i)
#pragma unroll
            for (int reg = 0; reg < 4; ++reg) {
                int    m = bm + wm + i * 16 + quad * 4 + reg;
                int    b = m >> 11, s = m & 2047;
                size_t base = ((size_t)(b * NH + h) * SEQ + s) * HD;
#pragma unroll
                for (int j = 0; j < 2; ++j) {
                    int   d1 = j * 16 + col;
                    float sn, cs;
                    if constexpr (PRE) {
                        cs = cosT[(s << 5) + d1];
                        sn = sinT[(s << 5) + d1];
                    } else {
                        float inv = __expf(-0.28782313662425574f * (float)d1);
                        sincosf((float)s * inv, &sn, &cs);
                    }
                    float x1 = acc[i][j][reg];
                    float x2 = acc[i][j + 2][reg];
                    dst[base + d1]      = f2bf(x1 * cs - x2 * sn);
                    dst[base + d1 + 32] = f2bf(x1 * sn + x2 * cs);
                }
            }
    }
}

// ---------------------------------------------------------------------------
// K2: causal flash attention. grid=(16, 16, 4) = 1024 blocks, ONE q-tile per
// block, qt = 15 - bx (heavy-first dispatch -> LPT balance; tail = 2-tile
// blocks). 4 blocks/CU (136 KB LDS) = 4 waves/SIMD (VGPR 104 <= 128 cap of
// launch_bounds(256,4)). Body = round-19: 4 waves x 32 q-rows (two strips),
// K/V fragment read once per jn/jd for both strips, XOR-swizzled Kt/Vt,
// defer-max THR=8 + per-lane partial l_i, setprio around MFMA.
// ---------------------------------------------------------------------------
__global__ __launch_bounds__(256, 4) void attn_kernel(
    const short* __restrict__ Q, const short* __restrict__ K,
    const short* __restrict__ VT, short* __restrict__ att) {
    const int b = blockIdx.z, h = blockIdx.y;
    const int tid = threadIdx.x, wave = tid >> 6, lane = tid & 63;
    const int quad = lane >> 4, col = lane & 15;
    const size_t hoff = (size_t)(b * NH + h) * SEQ * HD;
    const short* Qp  = Q + hoff;
    const short* Kp  = K + hoff;
    const short* VTp = VT + hoff;

    __shared__ __align__(16) short Kt[64 * 64];
    __shared__ __align__(16) short Vt[64 * 64];
    __shared__ __align__(16) short Ps[4 * 32 * PS_LD];

    const int r0 = tid >> 3;
    const int r1 = r0 + 32;
    const int c8 = (tid & 7) * 8;
    const int cs = c8 ^ ((r0 & 7) << 3);
    const int swc = (col & 7) << 3;
    const int cA  = (quad * 8) ^ swc;
    const int cB  = (32 + quad * 8) ^ swc;
    short* Pw = &Ps[wave * 32 * PS_LD];

    const int qt   = 15 - (int)blockIdx.x;      // heavy blocks dispatch first
    const int q0   = qt * 128 + wave * 32;
    const int tmax = 2 * qt + 1;

    bf16x8 aq[2][2];
#pragma unroll
    for (int s2 = 0; s2 < 2; ++s2) {
        aq[s2][0] = *(const bf16x8*)&Qp[(q0 + s2 * 16 + col) * HD + quad * 8];
        aq[s2][1] = *(const bf16x8*)&Qp[(q0 + s2 * 16 + col) * HD + 32 + quad * 8];
    }

    float m_i[2][4], l_i[2][4];
    f32x4 o[2][4];
#pragma unroll
    for (int s2 = 0; s2 < 2; ++s2)
#pragma unroll
        for (int rr = 0; rr < 4; ++rr) {
            m_i[s2][rr] = NEGINF; l_i[s2][rr] = 0.f;
            o[s2][rr] = f32x4{0.f, 0.f, 0.f, 0.f};
        }

    short8 ka = *(const short8*)&Kp[r0 * HD + c8];
    short8 kb = *(const short8*)&Kp[r1 * HD + c8];
    short8 va = *(const short8*)&VTp[(size_t)r0 * SEQ + c8];
    short8 vb = *(const short8*)&VTp[(size_t)r1 * SEQ + c8];

#pragma unroll 1
    for (int t = 0; t <= tmax; ++t) {
        const int kt = t * 64;
        __syncthreads();
        *(short8*)&Kt[r0 * 64 + cs] = ka;
        *(short8*)&Kt[r1 * 64 + cs] = kb;
        *(short8*)&Vt[r0 * 64 + cs] = va;
        *(short8*)&Vt[r1 * 64 + cs] = vb;
        __syncthreads();

        if (t < tmax) {
            const int kn = kt + 64;
            ka = *(const short8*)&Kp[(kn + r0) * HD + c8];
            kb = *(const short8*)&Kp[(kn + r1) * HD + c8];
            va = *(const short8*)&VTp[(size_t)r0 * SEQ + kn + c8];
            vb = *(const short8*)&VTp[(size_t)r1 * SEQ + kn + c8];
        }

        if (kt > q0 + 31) continue;            // wave fully masked

        float p[2][4][4];
        __builtin_amdgcn_s_setprio(1);
#pragma unroll
        for (int jn = 0; jn < 4; ++jn) {
            bf16x8 b0 = *(const bf16x8*)&Kt[(jn * 16 + col) * 64 + cA];
            bf16x8 b1 = *(const bf16x8*)&Kt[(jn * 16 + col) * 64 + cB];
#pragma unroll
            for (int s2 = 0; s2 < 2; ++s2) {
                f32x4 s = f32x4{0.f, 0.f, 0.f, 0.f};
                s = MFMA16(aq[s2][0], b0, s);
                s = MFMA16(aq[s2][1], b1, s);
                if (t >= 2 * qt) {
#pragma unroll
                    for (int reg = 0; reg < 4; ++reg) {
                        int qr = q0 + s2 * 16 + quad * 4 + reg;
                        int kc = kt + jn * 16 + col;
                        p[s2][jn][reg] = (kc <= qr) ? s[reg] * 0.125f : NEGINF;
                    }
                } else {
#pragma unroll
                    for (int reg = 0; reg < 4; ++reg)
                        p[s2][jn][reg] = s[reg] * 0.125f;
                }
            }
        }
        __builtin_amdgcn_s_setprio(0);

#pragma unroll
        for (int s2 = 0; s2 < 2; ++s2) {
            float lm[4];
#pragma unroll
            for (int reg = 0; reg < 4; ++reg)
                lm[reg] = fmaxf(fmaxf(p[s2][0][reg], p[s2][1][reg]),
                                fmaxf(p[s2][2][reg], p[s2][3][reg]));
            int ok = (lm[0] <= m_i[s2][0] + 8.f) & (lm[1] <= m_i[s2][1] + 8.f) &
                     (lm[2] <= m_i[s2][2] + 8.f) & (lm[3] <= m_i[s2][3] + 8.f);
            if (__all(ok)) {
#pragma unroll
                for (int reg = 0; reg < 4; ++reg) {
                    float rs = 0.f;
#pragma unroll
                    for (int jn = 0; jn < 4; ++jn) {
                        p[s2][jn][reg] = __expf(p[s2][jn][reg] - m_i[s2][reg]);
                        rs += p[s2][jn][reg];
                    }
                    l_i[s2][reg] += rs;
                }
            } else {
                float alpha[4];
#pragma unroll
                for (int reg = 0; reg < 4; ++reg) {
                    float mx = lm[reg];
#pragma unroll
                    for (int off = 8; off >= 1; off >>= 1)
                        mx = fmaxf(mx, __shfl_xor(mx, off, 64));
                    float mn   = fmaxf(m_i[s2][reg], mx);
                    alpha[reg] = __expf(m_i[s2][reg] - mn);
                    float rs = 0.f;
#pragma unroll
                    for (int jn = 0; jn < 4; ++jn) {
                        p[s2][jn][reg] = __expf(p[s2][jn][reg] - mn);
                        rs += p[s2][jn][reg];
                    }
                    l_i[s2][reg] = l_i[s2][reg] * alpha[reg] + rs;
                    m_i[s2][reg] = mn;
                }
#pragma unroll
                for (int jd = 0; jd < 4; ++jd)
#pragma unroll
                    for (int reg = 0; reg < 4; ++reg)
                        o[s2][jd][reg] *= alpha[reg];
            }

#pragma unroll
            for (int jn = 0; jn < 4; ++jn)
#pragma unroll
                for (int reg = 0; reg < 4; ++reg)
                    Pw[(s2 * 16 + quad * 4 + reg) * PS_LD + jn * 16 + col] =
                        f2bf(p[s2][jn][reg]);
        }

        bf16x8 ap[2][2];
#pragma unroll
        for (int s2 = 0; s2 < 2; ++s2) {
            ap[s2][0] = *(const bf16x8*)&Pw[(s2 * 16 + col) * PS_LD + quad * 8];
            ap[s2][1] = *(const bf16x8*)&Pw[(s2 * 16 + col) * PS_LD + 32 + quad * 8];
        }
        __builtin_amdgcn_s_setprio(1);
#pragma unroll
        for (int jd = 0; jd < 4; ++jd) {
            bf16x8 bv0 = *(const bf16x8*)&Vt[(jd * 16 + col) * 64 + cA];
            bf16x8 bv1 = *(const bf16x8*)&Vt[(jd * 16 + col) * 64 + cB];
#pragma unroll
            for (int s2 = 0; s2 < 2; ++s2) {
                o[s2][jd] = MFMA16(ap[s2][0], bv0, o[s2][jd]);
                o[s2][jd] = MFMA16(ap[s2][1], bv1, o[s2][jd]);
            }
        }
        __builtin_amdgcn_s_setprio(0);
    }

    // epilogue per strip: reduce l partials across 16 col-lanes, store
#pragma unroll
    for (int s2 = 0; s2 < 2; ++s2) {
#pragma unroll
        for (int off = 8; off >= 1; off >>= 1)
#pragma unroll
            for (int reg = 0; reg < 4; ++reg)
                l_i[s2][reg] += __shfl_xor(l_i[s2][reg], off, 64);
        float inv_l[4];
#pragma unroll
        for (int reg = 0; reg < 4; ++reg) inv_l[reg] = 1.f / l_i[s2][reg];
#pragma unroll
        for (int jd = 0; jd < 4; ++jd)
#pragma unroll
            for (int reg = 0; reg < 4; ++reg) {
                int s = q0 + s2 * 16 + quad * 4 + reg;
                att[((size_t)(b * SEQ + s)) * DIM + h * HD + jd * 16 + col] =
                    f2bf(o[s2][jd][reg] * inv_l[reg]);
            }
    }
}

// ---------------------------------------------------------------------------
// K3: out = att @ Wout^T, FP32 output. grid=(8, 64). PRE: bf16 Wout + p2.
// ---------------------------------------------------------------------------
template <bool PRE>
__global__ __launch_bounds__(256, 2) void out_gemm_kernel(
    const short* __restrict__ A, const void* __restrict__ W,
    float* __restrict__ out) {
    __shared__ __align__(16) short As[2 * 8192];
    __shared__ __align__(16) short Bs[2 * 8192];
    const int bm = blockIdx.y * 128, bn = blockIdx.x * 128;
    const int lane = threadIdx.x & 63, wave = threadIdx.x >> 6;
    const int quad = lane >> 4, col = lane & 15;
    const int wm = (wave & 1) * 64, wn = (wave >> 1) * 64;

    f32x4 acc[4][4];
    if constexpr (PRE)
        gemm128_p2(A, (const short*)W, 1024, As, Bs, bm, bn, acc);
    else
        gemm128_core<false, true>(A, W, 1024, As, Bs, bm, bn, acc);

#pragma unroll
    for (int i = 0; i < 4; ++i)
#pragma unroll
        for (int reg = 0; reg < 4; ++reg) {
            int    m    = bm + wm + i * 16 + quad * 4 + reg;
            size_t base = (size_t)m * DIM + bn + wn;
#pragma unroll
            for (int j = 0; j < 4; ++j)
                out[base + j * 16 + col] = acc[i][j][reg];
        }
}

// ---------------------------------------------------------------------------
extern "C" void kernel_launch(void* const* d_in, const int* in_sizes, int n_in,
                              void* d_out, int out_size, void* d_ws, size_t ws_size,
                              hipStream_t stream) {
    const float* x    = nullptr;
    const float* Wqkv = nullptr;
    const float* Wout = nullptr;
    for (int i = 0; i < n_in; ++i) {
        switch (in_sizes[i]) {
            case 8388608: x    = (const float*)d_in[i]; break;
            case 3145728: Wqkv = (const float*)d_in[i]; break;
            case 1048576: Wout = (const float*)d_in[i]; break;
            default: break;
        }
    }
    if (!x || !Wqkv || !Wout) return;

    short* Q  = (short*)d_ws;
    short* K  = Q + BHSD;
    short* VT = K + BHSD;
    float* out = (float*)d_out;

    const size_t need_pre = (size_t)4 * BHSD * sizeof(short)
                          + BHSD * sizeof(short)
                          + (size_t)3145728 * sizeof(short)
                          + (size_t)1048576 * sizeof(short)
                          + (size_t)2 * 65536 * sizeof(float);

    if (ws_size >= need_pre) {
        short* att  = VT + BHSD;
        short* Xb   = att + BHSD;
        short* Wqb  = Xb + BHSD;
        short* Wob  = Wqb + 3145728;
        float* cosT = (float*)(Wob + 1048576);
        float* sinT = cosT + 65536;

        prep_kernel<<<dim3(2048), 256, 0, stream>>>(x, Wqkv, Wout, Xb, Wqb, Wob, cosT, sinT);
        qkv_rope_kernel<true><<<dim3(24, 64), 256, 0, stream>>>(
            Xb, Wqb, cosT, sinT, Q, K, VT);
        attn_kernel<<<dim3(16, NH, BATCH), 256, 0, stream>>>(Q, K, VT, att);
        out_gemm_kernel<true><<<dim3(8, 64), 256, 0, stream>>>(att, Wob, out);
    } else {
        qkv_rope_kernel<false><<<dim3(24, 64), 256, 0, stream>>>(
            x, Wqkv, nullptr, nullptr, Q, K, VT);

        const bool direct = ws_size >= (size_t)4 * BHSD * sizeof(short);
        short* att_dst = direct ? (VT + BHSD) : (short*)d_out;
        attn_kernel<<<dim3(16, NH, BATCH), 256, 0, stream>>>(Q, K, VT, att_dst);

        short* att = att_dst;
        if (!direct) {
            att = (short*)d_ws;
            hipMemcpyAsync(att, att_dst, BHSD * sizeof(short), hipMemcpyDeviceToDevice, stream);
        }
        out_gemm_kernel<false><<<dim3(8, 64), 256, 0, stream>>>(att, Wout, out);
    }
}

// Round 12
// 342.277 us; speedup vs baseline: 1.5059x; 1.5059x over previous
//
#include <hip/hip_runtime.h>
#include <math.h>

// ---------------------------------------------------------------------------
// Round 23 — fix round-22's spill: attn launch_bounds (256,4) -> (256,2).
//   The (256,4) bound capped VGPR at 64 -> ~104-VGPR working set spilled to
//   scratch (WRITE_SIZE 16->437 MB, MfmaUtil 4.2%). At VGPR=104 the HW can
//   already run 4 waves/SIMD (416<=512) and LDS 34.8KB allows 4 blocks/CU,
//   so the (256,2) bound gets the intended occupancy WITHOUT the cap.
//   Grid structure kept: 1024 blocks, one q-tile per block, qt=15-bx
//   (heavy-first LPT). Body = round-19 structure.
//   K0/K1/K3 unchanged (prep; p2 gload_lds GEMM + table RoPE; out GEMM).
// ---------------------------------------------------------------------------

typedef __attribute__((ext_vector_type(8))) __bf16 bf16x8;
typedef __attribute__((ext_vector_type(8))) short  short8;
typedef __attribute__((ext_vector_type(4))) short  s16x4;
typedef __attribute__((ext_vector_type(4))) float  f32x4;

#define MFMA16(a, b, c) __builtin_amdgcn_mfma_f32_16x16x32_bf16((a), (b), (c), 0, 0, 0)

static constexpr int    BATCH = 4;
static constexpr int    SEQ   = 2048;
static constexpr int    DIM   = 1024;
static constexpr int    NH    = 16;
static constexpr int    HD    = 64;
static constexpr size_t BHSD  = (size_t)BATCH * NH * SEQ * HD;  // 8388608
static constexpr float  NEGINF = -1e9f;
static constexpr int    PS_LD  = 72;

__device__ __forceinline__ short f2bf(float f) {
    union { float f; unsigned u; } v; v.f = f;
    unsigned r = v.u + 0x7fffu + ((v.u >> 16) & 1u);  // RNE
    return (short)(r >> 16);
}

__device__ __forceinline__ short8 cvt8(const f32x4 lo, const f32x4 hi) {
    short8 r;
    r[0] = f2bf(lo[0]); r[1] = f2bf(lo[1]); r[2] = f2bf(lo[2]); r[3] = f2bf(lo[3]);
    r[4] = f2bf(hi[0]); r[5] = f2bf(hi[1]); r[6] = f2bf(hi[2]); r[7] = f2bf(hi[3]);
    return r;
}

template <bool F32>
__device__ __forceinline__ short8 ld8(const void* p, size_t row, int K, int k) {
    if constexpr (F32) {
        const float* f = (const float*)p;
        f32x4 lo = *(const f32x4*)&f[row * (size_t)K + k];
        f32x4 hi = *(const f32x4*)&f[row * (size_t)K + k + 4];
        return cvt8(lo, hi);
    } else {
        const short* s = (const short*)p;
        return *(const short8*)&s[row * (size_t)K + k];
    }
}

__device__ __forceinline__ void gload16(const void* g, void* lds) {
    __builtin_amdgcn_global_load_lds(
        (const __attribute__((address_space(1))) void*)g,
        (__attribute__((address_space(3))) void*)lds, 16, 0, 0);
}

// ---------------------------------------------------------------------------
// K0: one-shot bf16 conversion of X/Wqkv/Wout + RoPE trig tables.
// ---------------------------------------------------------------------------
__global__ __launch_bounds__(256) void prep_kernel(
    const float* __restrict__ X, const float* __restrict__ Wq,
    const float* __restrict__ Wo, short* __restrict__ Xb,
    short* __restrict__ Wqb, short* __restrict__ Wob,
    float* __restrict__ cosT, float* __restrict__ sinT) {
    const int stride = gridDim.x * blockDim.x;
    for (int idx = blockIdx.x * blockDim.x + threadIdx.x; idx < 3211264; idx += stride) {
        if (idx < 3145728) {
            const float* src; short* dst; int off;
            if (idx < 2097152)      { src = X;  dst = Xb;  off = idx; }
            else if (idx < 2883584) { src = Wq; dst = Wqb; off = idx - 2097152; }
            else                    { src = Wo; dst = Wob; off = idx - 2883584; }
            f32x4 v = *(const f32x4*)&src[(size_t)off * 4];
            s16x4 r;
            r[0] = f2bf(v[0]); r[1] = f2bf(v[1]); r[2] = f2bf(v[2]); r[3] = f2bf(v[3]);
            *(s16x4*)&dst[(size_t)off * 4] = r;
        } else {
            int r = idx - 3145728;
            int s = r >> 5, d = r & 31;
            float ang = (float)s * __expf(-0.28782313662425574f * (float)d);
            float sn, cs;
            sincosf(ang, &sn, &cs);
            cosT[r] = cs; sinT[r] = sn;
        }
    }
}

// ---------------------------------------------------------------------------
// GEMM core (fallback, reg-staged fp32): C(128x128) += A(128xK)*B(128xK)^T.
// ---------------------------------------------------------------------------
template <bool AF32, bool BF32>
__device__ __forceinline__ void gemm128_core(
    const void* __restrict__ A, const void* __restrict__ B, int K,
    short* As, short* Bs, int bm, int bn, f32x4 acc[4][4]) {
    const int tid  = threadIdx.x;
    const int lane = tid & 63;
    const int wave = tid >> 6;
    const int quad = lane >> 4;
    const int col  = lane & 15;
    const int wm   = (wave & 1) * 64;
    const int wn   = (wave >> 1) * 64;

    const int r0 = tid >> 2;
    const int r1 = (tid + 256) >> 2;
    const int ko = (tid & 3) * 8;

#pragma unroll
    for (int i = 0; i < 4; ++i)
#pragma unroll
        for (int j = 0; j < 4; ++j) acc[i][j] = f32x4{0.f, 0.f, 0.f, 0.f};

#pragma unroll 1
    for (int k0 = 0; k0 < K; k0 += 32) {
        short8 a0 = ld8<AF32>(A, (size_t)(bm + r0), K, k0 + ko);
        short8 a1 = ld8<AF32>(A, (size_t)(bm + r1), K, k0 + ko);
        short8 b0 = ld8<BF32>(B, (size_t)(bn + r0), K, k0 + ko);
        short8 b1 = ld8<BF32>(B, (size_t)(bn + r1), K, k0 + ko);
        __syncthreads();
        *(short8*)&As[tid * 8]         = a0;
        *(short8*)&As[(tid + 256) * 8] = a1;
        *(short8*)&Bs[tid * 8]         = b0;
        *(short8*)&Bs[(tid + 256) * 8] = b1;
        __syncthreads();

        bf16x8 af[4], bfr[4];
#pragma unroll
        for (int i = 0; i < 4; ++i)
            af[i] = *(const bf16x8*)&As[(wm + i * 16 + col) * 32 + quad * 8];
#pragma unroll
        for (int j = 0; j < 4; ++j)
            bfr[j] = *(const bf16x8*)&Bs[(wn + j * 16 + col) * 32 + quad * 8];
#pragma unroll
        for (int i = 0; i < 4; ++i)
#pragma unroll
            for (int j = 0; j < 4; ++j)
                acc[i][j] = MFMA16(af[i], bfr[j], acc[i][j]);
    }
}

// ---------------------------------------------------------------------------
// GEMM core p2 (bf16): BK=64 dbuf gload_lds, counted vmcnt, raw barriers,
// source-pre-swizzled LDS.
// ---------------------------------------------------------------------------
__device__ __forceinline__ void gemm128_p2(
    const short* __restrict__ A, const short* __restrict__ B, int K,
    short* As, short* Bs, int bm, int bn, f32x4 acc[4][4]) {
    const int tid  = threadIdx.x;
    const int lane = tid & 63;
    const int wave = tid >> 6;
    const int quad = lane >> 4;
    const int col  = lane & 15;
    const int wm   = (wave & 1) * 64;
    const int wn   = (wave >> 1) * 64;

    const int nt = K >> 6;
    const int rr = tid >> 3;
    const int swk = (((tid & 7) ^ (rr & 7)) << 3);
    const short* Ab = &A[(size_t)(bm + rr) * K + swk];
    const short* Bb = &B[(size_t)(bn + rr) * K + swk];

#pragma unroll
    for (int i = 0; i < 4; ++i)
#pragma unroll
        for (int j = 0; j < 4; ++j) acc[i][j] = f32x4{0.f, 0.f, 0.f, 0.f};

#define STAGE_TILE(c)                                                         \
    {                                                                         \
        const int s_ = (c) & 1;                                               \
        const int k0_ = (c) << 6;                                             \
        _Pragma("unroll")                                                     \
        for (int q = 0; q < 4; ++q) {                                         \
            gload16(Ab + (size_t)(q * 32) * K + k0_,                          \
                    &As[s_ * 8192 + q * 2048 + wave * 512]);                  \
            gload16(Bb + (size_t)(q * 32) * K + k0_,                          \
                    &Bs[s_ * 8192 + q * 2048 + wave * 512]);                  \
        }                                                                     \
    }

    STAGE_TILE(0);
    STAGE_TILE(1);

    const int pc0 = ((quad) ^ (col & 7)) << 3;
    const int pc1 = ((4 | quad) ^ (col & 7)) << 3;

#pragma unroll 1
    for (int c = 0; c < nt; ++c) {
        const int s = c & 1;
        if (c + 1 < nt) { asm volatile("s_waitcnt vmcnt(8)" ::: "memory"); }
        else            { asm volatile("s_waitcnt vmcnt(0)" ::: "memory"); }
        __builtin_amdgcn_s_barrier();

        const short* Asl = &As[s * 8192];
        const short* Bsl = &Bs[s * 8192];
        bf16x8 af[4][2], bfr[4][2];
#pragma unroll
        for (int i = 0; i < 4; ++i) {
            const int r = (wm + i * 16 + col) * 64;
            af[i][0] = *(const bf16x8*)&Asl[r + pc0];
            af[i][1] = *(const bf16x8*)&Asl[r + pc1];
        }
#pragma unroll
        for (int j = 0; j < 4; ++j) {
            const int r = (wn + j * 16 + col) * 64;
            bfr[j][0] = *(const bf16x8*)&Bsl[r + pc0];
            bfr[j][1] = *(const bf16x8*)&Bsl[r + pc1];
        }
#pragma unroll
        for (int kk = 0; kk < 2; ++kk)
#pragma unroll
            for (int i = 0; i < 4; ++i)
#pragma unroll
                for (int j = 0; j < 4; ++j)
                    acc[i][j] = MFMA16(af[i][kk], bfr[j][kk], acc[i][j]);

        __builtin_amdgcn_s_barrier();
        if (c + 2 < nt) STAGE_TILE(c + 2);
    }
#undef STAGE_TILE
}

// ---------------------------------------------------------------------------
// K1: QKV GEMM + RoPE. grid=(24, 64). Q,K row-major [B,H,S,D]; V transposed
// [B,H,D,S]. PRE: bf16 inputs (p2 core) + table RoPE.
// ---------------------------------------------------------------------------
template <bool PRE>
__global__ __launch_bounds__(256, 2) void qkv_rope_kernel(
    const void* __restrict__ X, const void* __restrict__ W,
    const float* __restrict__ cosT, const float* __restrict__ sinT,
    short* __restrict__ Qo, short* __restrict__ Ko, short* __restrict__ VT) {
    __shared__ __align__(16) short As[2 * 8192];
    __shared__ __align__(16) short Bs[2 * 8192];
    const int bm = blockIdx.y * 128, bn = blockIdx.x * 128;
    const int lane = threadIdx.x & 63, wave = threadIdx.x >> 6;
    const int quad = lane >> 4, col = lane & 15;
    const int wm = (wave & 1) * 64, wn = (wave >> 1) * 64;

    f32x4 acc[4][4];
    if constexpr (PRE)
        gemm128_p2((const short*)X, (const short*)W, 1024, As, Bs, bm, bn, acc);
    else
        gemm128_core<true, true>(X, W, 1024, As, Bs, bm, bn, acc);

    const int n0    = bn + wn;
    const int which = n0 >> 10;
    const int h     = (n0 >> 6) & 15;

    if (which == 2) {
#pragma unroll
        for (int i = 0; i < 4; ++i) {
            int    m = bm + wm + i * 16 + quad * 4;
            int    b = m >> 11, s = m & 2047;
            size_t rowb = (size_t)(b * NH + h) * HD;
#pragma unroll
            for (int j = 0; j < 4; ++j) {
                int   d = j * 16 + col;
                s16x4 pk;
                pk[0] = f2bf(acc[i][j][0]); pk[1] = f2bf(acc[i][j][1]);
                pk[2] = f2bf(acc[i][j][2]); pk[3] = f2bf(acc[i][j][3]);
                *(s16x4*)&VT[(rowb + d) * SEQ + s] = pk;
            }
        }
    } else {
        short* dst = which ? Ko : Qo;
#pragma unroll
        for (int i = 0; i < 4; ++i)
#pragma unroll
            for (int reg = 0; reg < 4; ++reg) {
                int    m = bm + wm + i * 16 + quad * 4 + reg;
                int    b = m >> 11, s = m & 2047;
                size_t base = ((size_t)(b * NH + h) * SEQ + s) * HD;
#pragma unroll
                for (int j = 0; j < 2; ++j) {
                    int   d1 = j * 16 + col;
                    float sn, cs;
                    if constexpr (PRE) {
                        cs = cosT[(s << 5) + d1];
                        sn = sinT[(s << 5) + d1];
                    } else {
                        float inv = __expf(-0.28782313662425574f * (float)d1);
                        sincosf((float)s * inv, &sn, &cs);
                    }
                    float x1 = acc[i][j][reg];
                    float x2 = acc[i][j + 2][reg];
                    dst[base + d1]      = f2bf(x1 * cs - x2 * sn);
                    dst[base + d1 + 32] = f2bf(x1 * sn + x2 * cs);
                }
            }
    }
}

// ---------------------------------------------------------------------------
// K2: causal flash attention. grid=(16, 16, 4) = 1024 blocks, ONE q-tile per
// block, qt = 15 - bx (heavy-first -> LPT balance). launch_bounds(256,2):
// NO VGPR cap beyond 256 — the real working set is ~104 VGPR, which the HW
// runs at 4 waves/SIMD (416<=512) with 4 blocks/CU by LDS (139<=160 KB).
// (256,4) capped VGPR at 64 and spilled ~880 MB/dispatch — round-22 lesson.
// Body = round-19: 4 waves x 32 q-rows (two strips), fragment amortization,
// XOR-swizzled Kt/Vt, defer-max THR=8 + per-lane partial l_i, setprio.
// ---------------------------------------------------------------------------
__global__ __launch_bounds__(256, 2) void attn_kernel(
    const short* __restrict__ Q, const short* __restrict__ K,
    const short* __restrict__ VT, short* __restrict__ att) {
    const int b = blockIdx.z, h = blockIdx.y;
    const int tid = threadIdx.x, wave = tid >> 6, lane = tid & 63;
    const int quad = lane >> 4, col = lane & 15;
    const size_t hoff = (size_t)(b * NH + h) * SEQ * HD;
    const short* Qp  = Q + hoff;
    const short* Kp  = K + hoff;
    const short* VTp = VT + hoff;

    __shared__ __align__(16) short Kt[64 * 64];
    __shared__ __align__(16) short Vt[64 * 64];
    __shared__ __align__(16) short Ps[4 * 32 * PS_LD];

    const int r0 = tid >> 3;
    const int r1 = r0 + 32;
    const int c8 = (tid & 7) * 8;
    const int cs = c8 ^ ((r0 & 7) << 3);
    const int swc = (col & 7) << 3;
    const int cA  = (quad * 8) ^ swc;
    const int cB  = (32 + quad * 8) ^ swc;
    short* Pw = &Ps[wave * 32 * PS_LD];

    const int qt   = 15 - (int)blockIdx.x;      // heavy blocks dispatch first
    const int q0   = qt * 128 + wave * 32;
    const int tmax = 2 * qt + 1;

    bf16x8 aq[2][2];
#pragma unroll
    for (int s2 = 0; s2 < 2; ++s2) {
        aq[s2][0] = *(const bf16x8*)&Qp[(q0 + s2 * 16 + col) * HD + quad * 8];
        aq[s2][1] = *(const bf16x8*)&Qp[(q0 + s2 * 16 + col) * HD + 32 + quad * 8];
    }

    float m_i[2][4], l_i[2][4];
    f32x4 o[2][4];
#pragma unroll
    for (int s2 = 0; s2 < 2; ++s2)
#pragma unroll
        for (int rr = 0; rr < 4; ++rr) {
            m_i[s2][rr] = NEGINF; l_i[s2][rr] = 0.f;
            o[s2][rr] = f32x4{0.f, 0.f, 0.f, 0.f};
        }

    short8 ka = *(const short8*)&Kp[r0 * HD + c8];
    short8 kb = *(const short8*)&Kp[r1 * HD + c8];
    short8 va = *(const short8*)&VTp[(size_t)r0 * SEQ + c8];
    short8 vb = *(const short8*)&VTp[(size_t)r1 * SEQ + c8];

#pragma unroll 1
    for (int t = 0; t <= tmax; ++t) {
        const int kt = t * 64;
        __syncthreads();
        *(short8*)&Kt[r0 * 64 + cs] = ka;
        *(short8*)&Kt[r1 * 64 + cs] = kb;
        *(short8*)&Vt[r0 * 64 + cs] = va;
        *(short8*)&Vt[r1 * 64 + cs] = vb;
        __syncthreads();

        if (t < tmax) {
            const int kn = kt + 64;
            ka = *(const short8*)&Kp[(kn + r0) * HD + c8];
            kb = *(const short8*)&Kp[(kn + r1) * HD + c8];
            va = *(const short8*)&VTp[(size_t)r0 * SEQ + kn + c8];
            vb = *(const short8*)&VTp[(size_t)r1 * SEQ + kn + c8];
        }

        if (kt > q0 + 31) continue;            // wave fully masked

        float p[2][4][4];
        __builtin_amdgcn_s_setprio(1);
#pragma unroll
        for (int jn = 0; jn < 4; ++jn) {
            bf16x8 b0 = *(const bf16x8*)&Kt[(jn * 16 + col) * 64 + cA];
            bf16x8 b1 = *(const bf16x8*)&Kt[(jn * 16 + col) * 64 + cB];
#pragma unroll
            for (int s2 = 0; s2 < 2; ++s2) {
                f32x4 s = f32x4{0.f, 0.f, 0.f, 0.f};
                s = MFMA16(aq[s2][0], b0, s);
                s = MFMA16(aq[s2][1], b1, s);
                if (t >= 2 * qt) {
#pragma unroll
                    for (int reg = 0; reg < 4; ++reg) {
                        int qr = q0 + s2 * 16 + quad * 4 + reg;
                        int kc = kt + jn * 16 + col;
                        p[s2][jn][reg] = (kc <= qr) ? s[reg] * 0.125f : NEGINF;
                    }
                } else {
#pragma unroll
                    for (int reg = 0; reg < 4; ++reg)
                        p[s2][jn][reg] = s[reg] * 0.125f;
                }
            }
        }
        __builtin_amdgcn_s_setprio(0);

#pragma unroll
        for (int s2 = 0; s2 < 2; ++s2) {
            float lm[4];
#pragma unroll
            for (int reg = 0; reg < 4; ++reg)
                lm[reg] = fmaxf(fmaxf(p[s2][0][reg], p[s2][1][reg]),
                                fmaxf(p[s2][2][reg], p[s2][3][reg]));
            int ok = (lm[0] <= m_i[s2][0] + 8.f) & (lm[1] <= m_i[s2][1] + 8.f) &
                     (lm[2] <= m_i[s2][2] + 8.f) & (lm[3] <= m_i[s2][3] + 8.f);
            if (__all(ok)) {
#pragma unroll
                for (int reg = 0; reg < 4; ++reg) {
                    float rs = 0.f;
#pragma unroll
                    for (int jn = 0; jn < 4; ++jn) {
                        p[s2][jn][reg] = __expf(p[s2][jn][reg] - m_i[s2][reg]);
                        rs += p[s2][jn][reg];
                    }
                    l_i[s2][reg] += rs;
                }
            } else {
                float alpha[4];
#pragma unroll
                for (int reg = 0; reg < 4; ++reg) {
                    float mx = lm[reg];
#pragma unroll
                    for (int off = 8; off >= 1; off >>= 1)
                        mx = fmaxf(mx, __shfl_xor(mx, off, 64));
                    float mn   = fmaxf(m_i[s2][reg], mx);
                    alpha[reg] = __expf(m_i[s2][reg] - mn);
                    float rs = 0.f;
#pragma unroll
                    for (int jn = 0; jn < 4; ++jn) {
                        p[s2][jn][reg] = __expf(p[s2][jn][reg] - mn);
                        rs += p[s2][jn][reg];
                    }
                    l_i[s2][reg] = l_i[s2][reg] * alpha[reg] + rs;
                    m_i[s2][reg] = mn;
                }
#pragma unroll
                for (int jd = 0; jd < 4; ++jd)
#pragma unroll
                    for (int reg = 0; reg < 4; ++reg)
                        o[s2][jd][reg] *= alpha[reg];
            }

#pragma unroll
            for (int jn = 0; jn < 4; ++jn)
#pragma unroll
                for (int reg = 0; reg < 4; ++reg)
                    Pw[(s2 * 16 + quad * 4 + reg) * PS_LD + jn * 16 + col] =
                        f2bf(p[s2][jn][reg]);
        }

        bf16x8 ap[2][2];
#pragma unroll
        for (int s2 = 0; s2 < 2; ++s2) {
            ap[s2][0] = *(const bf16x8*)&Pw[(s2 * 16 + col) * PS_LD + quad * 8];
            ap[s2][1] = *(const bf16x8*)&Pw[(s2 * 16 + col) * PS_LD + 32 + quad * 8];
        }
        __builtin_amdgcn_s_setprio(1);
#pragma unroll
        for (int jd = 0; jd < 4; ++jd) {
            bf16x8 bv0 = *(const bf16x8*)&Vt[(jd * 16 + col) * 64 + cA];
            bf16x8 bv1 = *(const bf16x8*)&Vt[(jd * 16 + col) * 64 + cB];
#pragma unroll
            for (int s2 = 0; s2 < 2; ++s2) {
                o[s2][jd] = MFMA16(ap[s2][0], bv0, o[s2][jd]);
                o[s2][jd] = MFMA16(ap[s2][1], bv1, o[s2][jd]);
            }
        }
        __builtin_amdgcn_s_setprio(0);
    }

    // epilogue per strip: reduce l partials across 16 col-lanes, store
#pragma unroll
    for (int s2 = 0; s2 < 2; ++s2) {
#pragma unroll
        for (int off = 8; off >= 1; off >>= 1)
#pragma unroll
            for (int reg = 0; reg < 4; ++reg)
                l_i[s2][reg] += __shfl_xor(l_i[s2][reg], off, 64);
        float inv_l[4];
#pragma unroll
        for (int reg = 0; reg < 4; ++reg) inv_l[reg] = 1.f / l_i[s2][reg];
#pragma unroll
        for (int jd = 0; jd < 4; ++jd)
#pragma unroll
            for (int reg = 0; reg < 4; ++reg) {
                int s = q0 + s2 * 16 + quad * 4 + reg;
                att[((size_t)(b * SEQ + s)) * DIM + h * HD + jd * 16 + col] =
                    f2bf(o[s2][jd][reg] * inv_l[reg]);
            }
    }
}

// ---------------------------------------------------------------------------
// K3: out = att @ Wout^T, FP32 output. grid=(8, 64). PRE: bf16 Wout + p2.
// ---------------------------------------------------------------------------
template <bool PRE>
__global__ __launch_bounds__(256, 2) void out_gemm_kernel(
    const short* __restrict__ A, const void* __restrict__ W,
    float* __restrict__ out) {
    __shared__ __align__(16) short As[2 * 8192];
    __shared__ __align__(16) short Bs[2 * 8192];
    const int bm = blockIdx.y * 128, bn = blockIdx.x * 128;
    const int lane = threadIdx.x & 63, wave = threadIdx.x >> 6;
    const int quad = lane >> 4, col = lane & 15;
    const int wm = (wave & 1) * 64, wn = (wave >> 1) * 64;

    f32x4 acc[4][4];
    if constexpr (PRE)
        gemm128_p2(A, (const short*)W, 1024, As, Bs, bm, bn, acc);
    else
        gemm128_core<false, true>(A, W, 1024, As, Bs, bm, bn, acc);

#pragma unroll
    for (int i = 0; i < 4; ++i)
#pragma unroll
        for (int reg = 0; reg < 4; ++reg) {
            int    m    = bm + wm + i * 16 + quad * 4 + reg;
            size_t base = (size_t)m * DIM + bn + wn;
#pragma unroll
            for (int j = 0; j < 4; ++j)
                out[base + j * 16 + col] = acc[i][j][reg];
        }
}

// ---------------------------------------------------------------------------
extern "C" void kernel_launch(void* const* d_in, const int* in_sizes, int n_in,
                              void* d_out, int out_size, void* d_ws, size_t ws_size,
                              hipStream_t stream) {
    const float* x    = nullptr;
    const float* Wqkv = nullptr;
    const float* Wout = nullptr;
    for (int i = 0; i < n_in; ++i) {
        switch (in_sizes[i]) {
            case 8388608: x    = (const float*)d_in[i]; break;
            case 3145728: Wqkv = (const float*)d_in[i]; break;
            case 1048576: Wout = (const float*)d_in[i]; break;
            default: break;
        }
    }
    if (!x || !Wqkv || !Wout) return;

    short* Q  = (short*)d_ws;
    short* K  = Q + BHSD;
    short* VT = K + BHSD;
    float* out = (float*)d_out;

    const size_t need_pre = (size_t)4 * BHSD * sizeof(short)
                          + BHSD * sizeof(short)
                          + (size_t)3145728 * sizeof(short)
                          + (size_t)1048576 * sizeof(short)
                          + (size_t)2 * 65536 * sizeof(float);

    if (ws_size >= need_pre) {
        short* att  = VT + BHSD;
        short* Xb   = att + BHSD;
        short* Wqb  = Xb + BHSD;
        short* Wob  = Wqb + 3145728;
        float* cosT = (float*)(Wob + 1048576);
        float* sinT = cosT + 65536;

        prep_kernel<<<dim3(2048), 256, 0, stream>>>(x, Wqkv, Wout, Xb, Wqb, Wob, cosT, sinT);
        qkv_rope_kernel<true><<<dim3(24, 64), 256, 0, stream>>>(
            Xb, Wqb, cosT, sinT, Q, K, VT);
        attn_kernel<<<dim3(16, NH, BATCH), 256, 0, stream>>>(Q, K, VT, att);
        out_gemm_kernel<true><<<dim3(8, 64), 256, 0, stream>>>(att, Wob, out);
    } else {
        qkv_rope_kernel<false><<<dim3(24, 64), 256, 0, stream>>>(
            x, Wqkv, nullptr, nullptr, Q, K, VT);

        const bool direct = ws_size >= (size_t)4 * BHSD * sizeof(short);
        short* att_dst = direct ? (VT + BHSD) : (short*)d_out;
        attn_kernel<<<dim3(16, NH, BATCH), 256, 0, stream>>>(Q, K, VT, att_dst);

        short* att = att_dst;
        if (!direct) {
            att = (short*)d_ws;
            hipMemcpyAsync(att, att_dst, BHSD * sizeof(short), hipMemcpyDeviceToDevice, stream);
        }
        out_gemm_kernel<false><<<dim3(8, 64), 256, 0, stream>>>(att, Wout, out);
    }
}

// Round 13
// 281.990 us; speedup vs baseline: 1.8278x; 1.2138x over previous
//
#include <hip/hip_runtime.h>
#include <math.h>

// ---------------------------------------------------------------------------
// Round 24 — fix the stride-256 qt-aliasing: balanced coset schedule.
//   MI355X places block id on CU (id mod 256) [8 XCDs x 32 CUs round-robin],
//   so a CU gets ids {j, j+256, j+512, j+768}. Round-23's grid had qt
//   constant on those cosets (16 | 256) -> per-CU load ratio 32:1 -> 11.4%
//   occupancy. New 1-D grid: k=id>>8, g=id&255, hb=g&63, jg=g>>6 and
//   qt = {15-jg, 8+jg, 7-jg, jg}[k] -> every CU's four blocks sum to 30
//   (68 tile-iters/CU, same as paired) with 4-way block parallelism.
//   Dispatch order heavy->light. Body unchanged (round-19 structure,
//   launch_bounds(256,2), VGPR~100, no spill).
//   K0/K1/K3 unchanged.
// ---------------------------------------------------------------------------

typedef __attribute__((ext_vector_type(8))) __bf16 bf16x8;
typedef __attribute__((ext_vector_type(8))) short  short8;
typedef __attribute__((ext_vector_type(4))) short  s16x4;
typedef __attribute__((ext_vector_type(4))) float  f32x4;

#define MFMA16(a, b, c) __builtin_amdgcn_mfma_f32_16x16x32_bf16((a), (b), (c), 0, 0, 0)

static constexpr int    BATCH = 4;
static constexpr int    SEQ   = 2048;
static constexpr int    DIM   = 1024;
static constexpr int    NH    = 16;
static constexpr int    HD    = 64;
static constexpr size_t BHSD  = (size_t)BATCH * NH * SEQ * HD;  // 8388608
static constexpr float  NEGINF = -1e9f;
static constexpr int    PS_LD  = 72;

__device__ __forceinline__ short f2bf(float f) {
    union { float f; unsigned u; } v; v.f = f;
    unsigned r = v.u + 0x7fffu + ((v.u >> 16) & 1u);  // RNE
    return (short)(r >> 16);
}

__device__ __forceinline__ short8 cvt8(const f32x4 lo, const f32x4 hi) {
    short8 r;
    r[0] = f2bf(lo[0]); r[1] = f2bf(lo[1]); r[2] = f2bf(lo[2]); r[3] = f2bf(lo[3]);
    r[4] = f2bf(hi[0]); r[5] = f2bf(hi[1]); r[6] = f2bf(hi[2]); r[7] = f2bf(hi[3]);
    return r;
}

template <bool F32>
__device__ __forceinline__ short8 ld8(const void* p, size_t row, int K, int k) {
    if constexpr (F32) {
        const float* f = (const float*)p;
        f32x4 lo = *(const f32x4*)&f[row * (size_t)K + k];
        f32x4 hi = *(const f32x4*)&f[row * (size_t)K + k + 4];
        return cvt8(lo, hi);
    } else {
        const short* s = (const short*)p;
        return *(const short8*)&s[row * (size_t)K + k];
    }
}

__device__ __forceinline__ void gload16(const void* g, void* lds) {
    __builtin_amdgcn_global_load_lds(
        (const __attribute__((address_space(1))) void*)g,
        (__attribute__((address_space(3))) void*)lds, 16, 0, 0);
}

// ---------------------------------------------------------------------------
// K0: one-shot bf16 conversion of X/Wqkv/Wout + RoPE trig tables.
// ---------------------------------------------------------------------------
__global__ __launch_bounds__(256) void prep_kernel(
    const float* __restrict__ X, const float* __restrict__ Wq,
    const float* __restrict__ Wo, short* __restrict__ Xb,
    short* __restrict__ Wqb, short* __restrict__ Wob,
    float* __restrict__ cosT, float* __restrict__ sinT) {
    const int stride = gridDim.x * blockDim.x;
    for (int idx = blockIdx.x * blockDim.x + threadIdx.x; idx < 3211264; idx += stride) {
        if (idx < 3145728) {
            const float* src; short* dst; int off;
            if (idx < 2097152)      { src = X;  dst = Xb;  off = idx; }
            else if (idx < 2883584) { src = Wq; dst = Wqb; off = idx - 2097152; }
            else                    { src = Wo; dst = Wob; off = idx - 2883584; }
            f32x4 v = *(const f32x4*)&src[(size_t)off * 4];
            s16x4 r;
            r[0] = f2bf(v[0]); r[1] = f2bf(v[1]); r[2] = f2bf(v[2]); r[3] = f2bf(v[3]);
            *(s16x4*)&dst[(size_t)off * 4] = r;
        } else {
            int r = idx - 3145728;
            int s = r >> 5, d = r & 31;
            float ang = (float)s * __expf(-0.28782313662425574f * (float)d);
            float sn, cs;
            sincosf(ang, &sn, &cs);
            cosT[r] = cs; sinT[r] = sn;
        }
    }
}

// ---------------------------------------------------------------------------
// GEMM core (fallback, reg-staged fp32): C(128x128) += A(128xK)*B(128xK)^T.
// ---------------------------------------------------------------------------
template <bool AF32, bool BF32>
__device__ __forceinline__ void gemm128_core(
    const void* __restrict__ A, const void* __restrict__ B, int K,
    short* As, short* Bs, int bm, int bn, f32x4 acc[4][4]) {
    const int tid  = threadIdx.x;
    const int lane = tid & 63;
    const int wave = tid >> 6;
    const int quad = lane >> 4;
    const int col  = lane & 15;
    const int wm   = (wave & 1) * 64;
    const int wn   = (wave >> 1) * 64;

    const int r0 = tid >> 2;
    const int r1 = (tid + 256) >> 2;
    const int ko = (tid & 3) * 8;

#pragma unroll
    for (int i = 0; i < 4; ++i)
#pragma unroll
        for (int j = 0; j < 4; ++j) acc[i][j] = f32x4{0.f, 0.f, 0.f, 0.f};

#pragma unroll 1
    for (int k0 = 0; k0 < K; k0 += 32) {
        short8 a0 = ld8<AF32>(A, (size_t)(bm + r0), K, k0 + ko);
        short8 a1 = ld8<AF32>(A, (size_t)(bm + r1), K, k0 + ko);
        short8 b0 = ld8<BF32>(B, (size_t)(bn + r0), K, k0 + ko);
        short8 b1 = ld8<BF32>(B, (size_t)(bn + r1), K, k0 + ko);
        __syncthreads();
        *(short8*)&As[tid * 8]         = a0;
        *(short8*)&As[(tid + 256) * 8] = a1;
        *(short8*)&Bs[tid * 8]         = b0;
        *(short8*)&Bs[(tid + 256) * 8] = b1;
        __syncthreads();

        bf16x8 af[4], bfr[4];
#pragma unroll
        for (int i = 0; i < 4; ++i)
            af[i] = *(const bf16x8*)&As[(wm + i * 16 + col) * 32 + quad * 8];
#pragma unroll
        for (int j = 0; j < 4; ++j)
            bfr[j] = *(const bf16x8*)&Bs[(wn + j * 16 + col) * 32 + quad * 8];
#pragma unroll
        for (int i = 0; i < 4; ++i)
#pragma unroll
            for (int j = 0; j < 4; ++j)
                acc[i][j] = MFMA16(af[i], bfr[j], acc[i][j]);
    }
}

// ---------------------------------------------------------------------------
// GEMM core p2 (bf16): BK=64 dbuf gload_lds, counted vmcnt, raw barriers,
// source-pre-swizzled LDS.
// ---------------------------------------------------------------------------
__device__ __forceinline__ void gemm128_p2(
    const short* __restrict__ A, const short* __restrict__ B, int K,
    short* As, short* Bs, int bm, int bn, f32x4 acc[4][4]) {
    const int tid  = threadIdx.x;
    const int lane = tid & 63;
    const int wave = tid >> 6;
    const int quad = lane >> 4;
    const int col  = lane & 15;
    const int wm   = (wave & 1) * 64;
    const int wn   = (wave >> 1) * 64;

    const int nt = K >> 6;
    const int rr = tid >> 3;
    const int swk = (((tid & 7) ^ (rr & 7)) << 3);
    const short* Ab = &A[(size_t)(bm + rr) * K + swk];
    const short* Bb = &B[(size_t)(bn + rr) * K + swk];

#pragma unroll
    for (int i = 0; i < 4; ++i)
#pragma unroll
        for (int j = 0; j < 4; ++j) acc[i][j] = f32x4{0.f, 0.f, 0.f, 0.f};

#define STAGE_TILE(c)                                                         \
    {                                                                         \
        const int s_ = (c) & 1;                                               \
        const int k0_ = (c) << 6;                                             \
        _Pragma("unroll")                                                     \
        for (int q = 0; q < 4; ++q) {                                         \
            gload16(Ab + (size_t)(q * 32) * K + k0_,                          \
                    &As[s_ * 8192 + q * 2048 + wave * 512]);                  \
            gload16(Bb + (size_t)(q * 32) * K + k0_,                          \
                    &Bs[s_ * 8192 + q * 2048 + wave * 512]);                  \
        }                                                                     \
    }

    STAGE_TILE(0);
    STAGE_TILE(1);

    const int pc0 = ((quad) ^ (col & 7)) << 3;
    const int pc1 = ((4 | quad) ^ (col & 7)) << 3;

#pragma unroll 1
    for (int c = 0; c < nt; ++c) {
        const int s = c & 1;
        if (c + 1 < nt) { asm volatile("s_waitcnt vmcnt(8)" ::: "memory"); }
        else            { asm volatile("s_waitcnt vmcnt(0)" ::: "memory"); }
        __builtin_amdgcn_s_barrier();

        const short* Asl = &As[s * 8192];
        const short* Bsl = &Bs[s * 8192];
        bf16x8 af[4][2], bfr[4][2];
#pragma unroll
        for (int i = 0; i < 4; ++i) {
            const int r = (wm + i * 16 + col) * 64;
            af[i][0] = *(const bf16x8*)&Asl[r + pc0];
            af[i][1] = *(const bf16x8*)&Asl[r + pc1];
        }
#pragma unroll
        for (int j = 0; j < 4; ++j) {
            const int r = (wn + j * 16 + col) * 64;
            bfr[j][0] = *(const bf16x8*)&Bsl[r + pc0];
            bfr[j][1] = *(const bf16x8*)&Bsl[r + pc1];
        }
#pragma unroll
        for (int kk = 0; kk < 2; ++kk)
#pragma unroll
            for (int i = 0; i < 4; ++i)
#pragma unroll
                for (int j = 0; j < 4; ++j)
                    acc[i][j] = MFMA16(af[i][kk], bfr[j][kk], acc[i][j]);

        __builtin_amdgcn_s_barrier();
        if (c + 2 < nt) STAGE_TILE(c + 2);
    }
#undef STAGE_TILE
}

// ---------------------------------------------------------------------------
// K1: QKV GEMM + RoPE. grid=(24, 64). Q,K row-major [B,H,S,D]; V transposed
// [B,H,D,S]. PRE: bf16 inputs (p2 core) + table RoPE.
// ---------------------------------------------------------------------------
template <bool PRE>
__global__ __launch_bounds__(256, 2) void qkv_rope_kernel(
    const void* __restrict__ X, const void* __restrict__ W,
    const float* __restrict__ cosT, const float* __restrict__ sinT,
    short* __restrict__ Qo, short* __restrict__ Ko, short* __restrict__ VT) {
    __shared__ __align__(16) short As[2 * 8192];
    __shared__ __align__(16) short Bs[2 * 8192];
    const int bm = blockIdx.y * 128, bn = blockIdx.x * 128;
    const int lane = threadIdx.x & 63, wave = threadIdx.x >> 6;
    const int quad = lane >> 4, col = lane & 15;
    const int wm = (wave & 1) * 64, wn = (wave >> 1) * 64;

    f32x4 acc[4][4];
    if constexpr (PRE)
        gemm128_p2((const short*)X, (const short*)W, 1024, As, Bs, bm, bn, acc);
    else
        gemm128_core<true, true>(X, W, 1024, As, Bs, bm, bn, acc);

    const int n0    = bn + wn;
    const int which = n0 >> 10;
    const int h     = (n0 >> 6) & 15;

    if (which == 2) {
#pragma unroll
        for (int i = 0; i < 4; ++i) {
            int    m = bm + wm + i * 16 + quad * 4;
            int    b = m >> 11, s = m & 2047;
            size_t rowb = (size_t)(b * NH + h) * HD;
#pragma unroll
            for (int j = 0; j < 4; ++j) {
                int   d = j * 16 + col;
                s16x4 pk;
                pk[0] = f2bf(acc[i][j][0]); pk[1] = f2bf(acc[i][j][1]);
                pk[2] = f2bf(acc[i][j][2]); pk[3] = f2bf(acc[i][j][3]);
                *(s16x4*)&VT[(rowb + d) * SEQ + s] = pk;
            }
        }
    } else {
        short* dst = which ? Ko : Qo;
#pragma unroll
        for (int i = 0; i < 4; ++i)
#pragma unroll
            for (int reg = 0; reg < 4; ++reg) {
                int    m = bm + wm + i * 16 + quad * 4 + reg;
                int    b = m >> 11, s = m & 2047;
                size_t base = ((size_t)(b * NH + h) * SEQ + s) * HD;
#pragma unroll
                for (int j = 0; j < 2; ++j) {
                    int   d1 = j * 16 + col;
                    float sn, cs;
                    if constexpr (PRE) {
                        cs = cosT[(s << 5) + d1];
                        sn = sinT[(s << 5) + d1];
                    } else {
                        float inv = __expf(-0.28782313662425574f * (float)d1);
                        sincosf((float)s * inv, &sn, &cs);
                    }
                    float x1 = acc[i][j][reg];
                    float x2 = acc[i][j + 2][reg];
                    dst[base + d1]      = f2bf(x1 * cs - x2 * sn);
                    dst[base + d1 + 32] = f2bf(x1 * sn + x2 * cs);
                }
            }
    }
}

// ---------------------------------------------------------------------------
// K2: causal flash attention. grid=(1024): id -> k=id>>8, g=id&255,
// hb=g&63 (h=hb&15, b=hb>>4), jg=g>>6, qt = {15-jg, 8+jg, 7-jg, jg}[k].
// Stride-256 cosets (one CU's 4 blocks) get qt values summing to 30 ->
// per-CU work 68 tile-iters, balanced; dispatch heavy->light. 4 blocks/CU
// (LDS 139KB, VGPR ~100 -> 16 waves/CU). Body = round-19 structure:
// 4 waves x 32 q-rows (two strips), fragment amortization, XOR-swizzled
// Kt/Vt, defer-max THR=8 + per-lane partial l_i, setprio around MFMA.
// ---------------------------------------------------------------------------
__global__ __launch_bounds__(256, 2) void attn_kernel(
    const short* __restrict__ Q, const short* __restrict__ K,
    const short* __restrict__ VT, short* __restrict__ att) {
    const int id = (int)blockIdx.x;
    const int k4 = id >> 8;                 // 0..3
    const int g  = id & 255;
    const int hb = g & 63;
    const int jg = g >> 6;                  // 0..3
    const int qt = (k4 == 0) ? 15 - jg : (k4 == 1) ? 8 + jg
                 : (k4 == 2) ? 7 - jg  : jg;
    const int h = hb & 15;
    const int b = hb >> 4;

    const int tid = threadIdx.x, wave = tid >> 6, lane = tid & 63;
    const int quad = lane >> 4, col = lane & 15;
    const size_t hoff = (size_t)(b * NH + h) * SEQ * HD;
    const short* Qp  = Q + hoff;
    const short* Kp  = K + hoff;
    const short* VTp = VT + hoff;

    __shared__ __align__(16) short Kt[64 * 64];
    __shared__ __align__(16) short Vt[64 * 64];
    __shared__ __align__(16) short Ps[4 * 32 * PS_LD];

    const int r0 = tid >> 3;
    const int r1 = r0 + 32;
    const int c8 = (tid & 7) * 8;
    const int cs = c8 ^ ((r0 & 7) << 3);
    const int swc = (col & 7) << 3;
    const int cA  = (quad * 8) ^ swc;
    const int cB  = (32 + quad * 8) ^ swc;
    short* Pw = &Ps[wave * 32 * PS_LD];

    const int q0   = qt * 128 + wave * 32;
    const int tmax = 2 * qt + 1;

    bf16x8 aq[2][2];
#pragma unroll
    for (int s2 = 0; s2 < 2; ++s2) {
        aq[s2][0] = *(const bf16x8*)&Qp[(q0 + s2 * 16 + col) * HD + quad * 8];
        aq[s2][1] = *(const bf16x8*)&Qp[(q0 + s2 * 16 + col) * HD + 32 + quad * 8];
    }

    float m_i[2][4], l_i[2][4];
    f32x4 o[2][4];
#pragma unroll
    for (int s2 = 0; s2 < 2; ++s2)
#pragma unroll
        for (int rr = 0; rr < 4; ++rr) {
            m_i[s2][rr] = NEGINF; l_i[s2][rr] = 0.f;
            o[s2][rr] = f32x4{0.f, 0.f, 0.f, 0.f};
        }

    short8 ka = *(const short8*)&Kp[r0 * HD + c8];
    short8 kb = *(const short8*)&Kp[r1 * HD + c8];
    short8 va = *(const short8*)&VTp[(size_t)r0 * SEQ + c8];
    short8 vb = *(const short8*)&VTp[(size_t)r1 * SEQ + c8];

#pragma unroll 1
    for (int t = 0; t <= tmax; ++t) {
        const int kt = t * 64;
        __syncthreads();
        *(short8*)&Kt[r0 * 64 + cs] = ka;
        *(short8*)&Kt[r1 * 64 + cs] = kb;
        *(short8*)&Vt[r0 * 64 + cs] = va;
        *(short8*)&Vt[r1 * 64 + cs] = vb;
        __syncthreads();

        if (t < tmax) {
            const int kn = kt + 64;
            ka = *(const short8*)&Kp[(kn + r0) * HD + c8];
            kb = *(const short8*)&Kp[(kn + r1) * HD + c8];
            va = *(const short8*)&VTp[(size_t)r0 * SEQ + kn + c8];
            vb = *(const short8*)&VTp[(size_t)r1 * SEQ + kn + c8];
        }

        if (kt > q0 + 31) continue;            // wave fully masked

        float p[2][4][4];
        __builtin_amdgcn_s_setprio(1);
#pragma unroll
        for (int jn = 0; jn < 4; ++jn) {
            bf16x8 b0 = *(const bf16x8*)&Kt[(jn * 16 + col) * 64 + cA];
            bf16x8 b1 = *(const bf16x8*)&Kt[(jn * 16 + col) * 64 + cB];
#pragma unroll
            for (int s2 = 0; s2 < 2; ++s2) {
                f32x4 s = f32x4{0.f, 0.f, 0.f, 0.f};
                s = MFMA16(aq[s2][0], b0, s);
                s = MFMA16(aq[s2][1], b1, s);
                if (t >= 2 * qt) {
#pragma unroll
                    for (int reg = 0; reg < 4; ++reg) {
                        int qr = q0 + s2 * 16 + quad * 4 + reg;
                        int kc = kt + jn * 16 + col;
                        p[s2][jn][reg] = (kc <= qr) ? s[reg] * 0.125f : NEGINF;
                    }
                } else {
#pragma unroll
                    for (int reg = 0; reg < 4; ++reg)
                        p[s2][jn][reg] = s[reg] * 0.125f;
                }
            }
        }
        __builtin_amdgcn_s_setprio(0);

#pragma unroll
        for (int s2 = 0; s2 < 2; ++s2) {
            float lm[4];
#pragma unroll
            for (int reg = 0; reg < 4; ++reg)
                lm[reg] = fmaxf(fmaxf(p[s2][0][reg], p[s2][1][reg]),
                                fmaxf(p[s2][2][reg], p[s2][3][reg]));
            int ok = (lm[0] <= m_i[s2][0] + 8.f) & (lm[1] <= m_i[s2][1] + 8.f) &
                     (lm[2] <= m_i[s2][2] + 8.f) & (lm[3] <= m_i[s2][3] + 8.f);
            if (__all(ok)) {
#pragma unroll
                for (int reg = 0; reg < 4; ++reg) {
                    float rs = 0.f;
#pragma unroll
                    for (int jn = 0; jn < 4; ++jn) {
                        p[s2][jn][reg] = __expf(p[s2][jn][reg] - m_i[s2][reg]);
                        rs += p[s2][jn][reg];
                    }
                    l_i[s2][reg] += rs;
                }
            } else {
                float alpha[4];
#pragma unroll
                for (int reg = 0; reg < 4; ++reg) {
                    float mx = lm[reg];
#pragma unroll
                    for (int off = 8; off >= 1; off >>= 1)
                        mx = fmaxf(mx, __shfl_xor(mx, off, 64));
                    float mn   = fmaxf(m_i[s2][reg], mx);
                    alpha[reg] = __expf(m_i[s2][reg] - mn);
                    float rs = 0.f;
#pragma unroll
                    for (int jn = 0; jn < 4; ++jn) {
                        p[s2][jn][reg] = __expf(p[s2][jn][reg] - mn);
                        rs += p[s2][jn][reg];
                    }
                    l_i[s2][reg] = l_i[s2][reg] * alpha[reg] + rs;
                    m_i[s2][reg] = mn;
                }
#pragma unroll
                for (int jd = 0; jd < 4; ++jd)
#pragma unroll
                    for (int reg = 0; reg < 4; ++reg)
                        o[s2][jd][reg] *= alpha[reg];
            }

#pragma unroll
            for (int jn = 0; jn < 4; ++jn)
#pragma unroll
                for (int reg = 0; reg < 4; ++reg)
                    Pw[(s2 * 16 + quad * 4 + reg) * PS_LD + jn * 16 + col] =
                        f2bf(p[s2][jn][reg]);
        }

        bf16x8 ap[2][2];
#pragma unroll
        for (int s2 = 0; s2 < 2; ++s2) {
            ap[s2][0] = *(const bf16x8*)&Pw[(s2 * 16 + col) * PS_LD + quad * 8];
            ap[s2][1] = *(const bf16x8*)&Pw[(s2 * 16 + col) * PS_LD + 32 + quad * 8];
        }
        __builtin_amdgcn_s_setprio(1);
#pragma unroll
        for (int jd = 0; jd < 4; ++jd) {
            bf16x8 bv0 = *(const bf16x8*)&Vt[(jd * 16 + col) * 64 + cA];
            bf16x8 bv1 = *(const bf16x8*)&Vt[(jd * 16 + col) * 64 + cB];
#pragma unroll
            for (int s2 = 0; s2 < 2; ++s2) {
                o[s2][jd] = MFMA16(ap[s2][0], bv0, o[s2][jd]);
                o[s2][jd] = MFMA16(ap[s2][1], bv1, o[s2][jd]);
            }
        }
        __builtin_amdgcn_s_setprio(0);
    }

    // epilogue per strip: reduce l partials across 16 col-lanes, store
#pragma unroll
    for (int s2 = 0; s2 < 2; ++s2) {
#pragma unroll
        for (int off = 8; off >= 1; off >>= 1)
#pragma unroll
            for (int reg = 0; reg < 4; ++reg)
                l_i[s2][reg] += __shfl_xor(l_i[s2][reg], off, 64);
        float inv_l[4];
#pragma unroll
        for (int reg = 0; reg < 4; ++reg) inv_l[reg] = 1.f / l_i[s2][reg];
#pragma unroll
        for (int jd = 0; jd < 4; ++jd)
#pragma unroll
            for (int reg = 0; reg < 4; ++reg) {
                int s = q0 + s2 * 16 + quad * 4 + reg;
                att[((size_t)(b * SEQ + s)) * DIM + h * HD + jd * 16 + col] =
                    f2bf(o[s2][jd][reg] * inv_l[reg]);
            }
    }
}

// ---------------------------------------------------------------------------
// K3: out = att @ Wout^T, FP32 output. grid=(8, 64). PRE: bf16 Wout + p2.
// ---------------------------------------------------------------------------
template <bool PRE>
__global__ __launch_bounds__(256, 2) void out_gemm_kernel(
    const short* __restrict__ A, const void* __restrict__ W,
    float* __restrict__ out) {
    __shared__ __align__(16) short As[2 * 8192];
    __shared__ __align__(16) short Bs[2 * 8192];
    const int bm = blockIdx.y * 128, bn = blockIdx.x * 128;
    const int lane = threadIdx.x & 63, wave = threadIdx.x >> 6;
    const int quad = lane >> 4, col = lane & 15;
    const int wm = (wave & 1) * 64, wn = (wave >> 1) * 64;

    f32x4 acc[4][4];
    if constexpr (PRE)
        gemm128_p2(A, (const short*)W, 1024, As, Bs, bm, bn, acc);
    else
        gemm128_core<false, true>(A, W, 1024, As, Bs, bm, bn, acc);

#pragma unroll
    for (int i = 0; i < 4; ++i)
#pragma unroll
        for (int reg = 0; reg < 4; ++reg) {
            int    m    = bm + wm + i * 16 + quad * 4 + reg;
            size_t base = (size_t)m * DIM + bn + wn;
#pragma unroll
            for (int j = 0; j < 4; ++j)
                out[base + j * 16 + col] = acc[i][j][reg];
        }
}

// ---------------------------------------------------------------------------
extern "C" void kernel_launch(void* const* d_in, const int* in_sizes, int n_in,
                              void* d_out, int out_size, void* d_ws, size_t ws_size,
                              hipStream_t stream) {
    const float* x    = nullptr;
    const float* Wqkv = nullptr;
    const float* Wout = nullptr;
    for (int i = 0; i < n_in; ++i) {
        switch (in_sizes[i]) {
            case 8388608: x    = (const float*)d_in[i]; break;
            case 3145728: Wqkv = (const float*)d_in[i]; break;
            case 1048576: Wout = (const float*)d_in[i]; break;
            default: break;
        }
    }
    if (!x || !Wqkv || !Wout) return;

    short* Q  = (short*)d_ws;
    short* K  = Q + BHSD;
    short* VT = K + BHSD;
    float* out = (float*)d_out;

    const size_t need_pre = (size_t)4 * BHSD * sizeof(short)
                          + BHSD * sizeof(short)
                          + (size_t)3145728 * sizeof(short)
                          + (size_t)1048576 * sizeof(short)
                          + (size_t)2 * 65536 * sizeof(float);

    if (ws_size >= need_pre) {
        short* att  = VT + BHSD;
        short* Xb   = att + BHSD;
        short* Wqb  = Xb + BHSD;
        short* Wob  = Wqb + 3145728;
        float* cosT = (float*)(Wob + 1048576);
        float* sinT = cosT + 65536;

        prep_kernel<<<dim3(2048), 256, 0, stream>>>(x, Wqkv, Wout, Xb, Wqb, Wob, cosT, sinT);
        qkv_rope_kernel<true><<<dim3(24, 64), 256, 0, stream>>>(
            Xb, Wqb, cosT, sinT, Q, K, VT);
        attn_kernel<<<dim3(1024), 256, 0, stream>>>(Q, K, VT, att);
        out_gemm_kernel<true><<<dim3(8, 64), 256, 0, stream>>>(att, Wob, out);
    } else {
        qkv_rope_kernel<false><<<dim3(24, 64), 256, 0, stream>>>(
            x, Wqkv, nullptr, nullptr, Q, K, VT);

        const bool direct = ws_size >= (size_t)4 * BHSD * sizeof(short);
        short* att_dst = direct ? (VT + BHSD) : (short*)d_out;
        attn_kernel<<<dim3(1024), 256, 0, stream>>>(Q, K, VT, att_dst);

        short* att = att_dst;
        if (!direct) {
            att = (short*)d_ws;
            hipMemcpyAsync(att, att_dst, BHSD * sizeof(short), hipMemcpyDeviceToDevice, stream);
        }
        out_gemm_kernel<false><<<dim3(8, 64), 256, 0, stream>>>(att, Wout, out);
    }
}